// Round 1
// baseline (2806.934 us; speedup 1.0000x reference)
//
#include <hip/hip_runtime.h>

// Problem constants (from reference)
#define B_TOT 16384
#define T_STEPS 128
#define F_IN 29
#define K_HID 512
#define D_IN 32

#define NB 64   // batch elems per workgroup (lane = batch elem)
#define NW 8    // waves per workgroup; wave w owns nodes [64w, 64w+64)

// tanh(x) = 1 - 2/(exp(2x)+1); exp via v_exp, recip via v_rcp (approx, ~1ulp)
__device__ __forceinline__ float fast_tanh(float x) {
    float e = __expf(2.0f * x);                       // v_mul + v_exp_f32
    return 1.0f - 2.0f * __builtin_amdgcn_rcpf(e + 1.0f);
}

__global__ __launch_bounds__(512)
void narx_fwd(const float* __restrict__ X,   // [B][T][F]
              const float* __restrict__ y0,  // [B][3]
              const float* __restrict__ W1,  // [32][512]
              const float* __restrict__ b1,  // [512]
              const float* __restrict__ W2,  // [512]
              const float* __restrict__ b2,  // [1]
              float* __restrict__ out)       // [B][T]
{
    // W1 transposed in LDS: sW1[node][i], rows 16B-aligned for float4 reads
    __shared__ float sW1[K_HID][D_IN];          // 64 KB
    __shared__ float sB1[K_HID];                // 2 KB
    __shared__ float sW2[K_HID];                // 2 KB
    __shared__ float sX[NB * 31];               // stride 31 -> conflict-free
    __shared__ float sFb[3][NB];                // feedback state per chain
    __shared__ float sPartial[NW][NB];          // per-wave partial W2-dots

    const int tid  = threadIdx.x;
    const int lane = tid & 63;
    const int w    = tid >> 6;
    const int b    = blockIdx.x * NB + lane;

    // --- one-time staging ---
    // transposed W1 load: global side coalesced (consecutive tid -> consecutive k)
    #pragma unroll
    for (int i = 0; i < D_IN; ++i)
        sW1[tid][i] = W1[i * K_HID + tid];
    sB1[tid] = b1[tid];
    sW2[tid] = W2[tid];
    if (w < 3)
        sFb[w][lane] = y0[(size_t)b * 3 + w];   // fb[i] <- y0[:, i]
    const float b2v = b2[0];
    __syncthreads();

    const float* Xblk = X + (size_t)blockIdx.x * NB * T_STEPS * F_IN;

    for (int t = 0; t < T_STEPS; ++t) {
        // cooperative stage of this step's X rows: 64*29 floats, read once from HBM
        for (int j = tid; j < NB * F_IN; j += 512) {
            int bl = j / F_IN;            // magic-mul div
            int i  = j - bl * F_IN;
            sX[bl * 31 + i] = Xblk[bl * (T_STEPS * F_IN) + t * F_IN + i];
        }
        __syncthreads();   // barrier 1: sX ready, sFb (from prev step) visible

        // gather this lane's input vector into registers
        float x[D_IN];
        #pragma unroll
        for (int i = 0; i < F_IN; ++i) x[i] = sX[lane * 31 + i];
        x[29] = sFb[0][lane];
        x[30] = sFb[1][lane];
        x[31] = sFb[2][lane];

        // this wave's 64 hidden nodes
        float partial = 0.0f;
        const float* wbase = &sW1[w * 64][0];
        #pragma unroll 4
        for (int n = 0; n < 64; ++n) {
            float acc = sB1[w * 64 + n];
            const float4* wv4 = (const float4*)(wbase + n * D_IN);
            #pragma unroll
            for (int q = 0; q < 8; ++q) {
                float4 wv = wv4[q];        // ds_read_b128, broadcast (uniform addr)
                acc = fmaf(wv.x, x[4*q+0], acc);
                acc = fmaf(wv.y, x[4*q+1], acc);
                acc = fmaf(wv.z, x[4*q+2], acc);
                acc = fmaf(wv.w, x[4*q+3], acc);
            }
            float h = fast_tanh(acc);
            partial = fmaf(h, sW2[w * 64 + n], partial);
        }
        sPartial[w][lane] = partial;
        __syncthreads();   // barrier 2: partials ready; all sFb/sX reads done

        // only waves 0,1 need the final pred (fb update / output store)
        if (w < 2) {
            float pred = b2v;
            #pragma unroll
            for (int r = 0; r < NW; ++r) pred += sPartial[r][lane];
            if (w == 0) {
                // shift feedback: fb0 <- pred, fb1 <- old fb0, fb2 <- old fb1
                float f0 = sFb[0][lane], f1 = sFb[1][lane];
                sFb[0][lane] = pred;
                sFb[1][lane] = f0;
                sFb[2][lane] = f1;
            } else {
                out[(size_t)b * T_STEPS + t] = pred;
            }
        }
        // next iteration's barrier 1 orders the sFb write vs. next reads
    }
}

extern "C" void kernel_launch(void* const* d_in, const int* in_sizes, int n_in,
                              void* d_out, int out_size, void* d_ws, size_t ws_size,
                              hipStream_t stream) {
    const float* X  = (const float*)d_in[0];
    const float* y0 = (const float*)d_in[1];
    const float* W1 = (const float*)d_in[2];
    const float* b1 = (const float*)d_in[3];
    const float* W2 = (const float*)d_in[4];
    const float* b2 = (const float*)d_in[5];
    float* out = (float*)d_out;

    dim3 grid(B_TOT / NB);   // 256 workgroups, 1 per CU
    dim3 block(NW * 64);     // 512 threads = 8 waves
    narx_fwd<<<grid, block, 0, stream>>>(X, y0, W1, b1, W2, b2, out);
}

// Round 2
// 1353.648 us; speedup vs baseline: 2.0736x; 2.0736x over previous
//
#include <hip/hip_runtime.h>

#define B_TOT 16384
#define T_STEPS 128
#define F_IN 29
#define K_HID 512
#define D_IN 32

typedef __attribute__((ext_vector_type(8))) short short8;   // 8 bf16 = 4 VGPR (MFMA A/B frag)
typedef __attribute__((ext_vector_type(4))) float floatx4;  // MFMA C/D frag

// tanh(x) = 1 - 2/(exp(2x)+1)  — v_exp + v_rcp, ~1e-7 rel err, safe over full range
__device__ __forceinline__ float fast_tanh(float x) {
    float e = __expf(2.0f * x);
    return 1.0f - 2.0f * __builtin_amdgcn_rcpf(e + 1.0f);
}

__device__ __forceinline__ short bf16_hi_bits(float x) {
    return (short)(__float_as_uint(x) >> 16);          // truncate to bf16
}
__device__ __forceinline__ float bf16_hi_f(float x) {
    return __uint_as_float(__float_as_uint(x) & 0xffff0000u);
}

// Block: 256 threads = 4 waves. Block owns 16 batch rows; wave w owns nodes
// [128w, 128w+128) as 8 MFMA tiles. W1 fragments register-resident (bf16 hi/lo).
// bf16x3 compensated MFMA (hi*hi + hi*lo + lo*hi) ~= fp32 precision.
__global__ __launch_bounds__(256, 4)
void narx_mfma(const float* __restrict__ X,   // [B][T][29]
               const float* __restrict__ y0,  // [B][3]
               const float* __restrict__ W1,  // [32][512]
               const float* __restrict__ b1,  // [512]
               const float* __restrict__ W2,  // [512]
               const float* __restrict__ b2,  // [1]
               float* __restrict__ out)       // [B][T]
{
    __shared__ float sPart[2][4][16];   // [ping-pong][wave][batch row]

    const int tid  = threadIdx.x;
    const int lane = tid & 63;
    const int w    = tid >> 6;     // wave 0..3
    const int q    = lane >> 4;    // quad 0..3
    const int m    = lane & 15;    // A: batch row in tile; B: node col in tile
    const size_t row = (size_t)blockIdx.x * 16 + m;

    // ---- one-time: W1 B-fragments (hi/lo), b1, W2 into registers ----
    // B-frag layout: B[k][n], n = lane&15, k = quad*8 + j
    short8 whi[8], wlo[8];
    float b1v[8], w2v[8];
    #pragma unroll
    for (int nt = 0; nt < 8; ++nt) {
        int node = w * 128 + nt * 16 + m;
        #pragma unroll
        for (int j = 0; j < 8; ++j) {
            int k = q * 8 + j;
            float v  = W1[k * K_HID + node];
            float hf = bf16_hi_f(v);
            whi[nt][j] = bf16_hi_bits(v);
            wlo[nt][j] = bf16_hi_bits(v - hf);
        }
        b1v[nt] = b1[node];
        w2v[nt] = W2[node];
    }
    const float b2v = b2[0];

    // every lane tracks fb for its own row m (lanes 48..63 feed it into the A-frag)
    float fb0 = y0[row * 3 + 0];
    float fb1 = y0[row * 3 + 1];
    float fb2 = y0[row * 3 + 2];

    const float* Xrow = X + row * (T_STEPS * F_IN);

    for (int t = 0; t < T_STEPS; ++t) {
        // ---- build A fragment: A[m][k], m = lane&15, k = quad*8 + j ----
        const float* Xp = Xrow + t * F_IN;
        float xv[8];
        #pragma unroll
        for (int j = 0; j < 8; ++j) {
            int k = q * 8 + j;
            xv[j] = Xp[k < 29 ? k : 28];   // clamp keeps loads in-bounds
        }
        if (q == 3) { xv[5] = fb0; xv[6] = fb1; xv[7] = fb2; }  // k = 29,30,31

        short8 ahi, alo;
        #pragma unroll
        for (int j = 0; j < 8; ++j) {
            float hf = bf16_hi_f(xv[j]);
            ahi[j] = bf16_hi_bits(xv[j]);
            alo[j] = bf16_hi_bits(xv[j] - hf);
        }

        // ---- 8 node-tiles: 3 MFMAs each (compensated), tanh + W2 epilogue ----
        float pa0 = 0.f, pa1 = 0.f, pa2 = 0.f, pa3 = 0.f;
        #pragma unroll
        for (int nt = 0; nt < 8; ++nt) {
            floatx4 c = {b1v[nt], b1v[nt], b1v[nt], b1v[nt]};
            c = __builtin_amdgcn_mfma_f32_16x16x32_bf16(ahi, whi[nt], c, 0, 0, 0);
            c = __builtin_amdgcn_mfma_f32_16x16x32_bf16(ahi, wlo[nt], c, 0, 0, 0);
            c = __builtin_amdgcn_mfma_f32_16x16x32_bf16(alo, whi[nt], c, 0, 0, 0);
            // C layout: col(node) = lane&15, row(batch) = quad*4 + reg
            pa0 = fmaf(fast_tanh(c[0]), w2v[nt], pa0);
            pa1 = fmaf(fast_tanh(c[1]), w2v[nt], pa1);
            pa2 = fmaf(fast_tanh(c[2]), w2v[nt], pa2);
            pa3 = fmaf(fast_tanh(c[3]), w2v[nt], pa3);
        }

        // ---- reduce over the 16 node-columns (lanes xor 1,2,4,8) ----
        #pragma unroll
        for (int mask = 1; mask <= 8; mask <<= 1) {
            pa0 += __shfl_xor(pa0, mask, 64);
            pa1 += __shfl_xor(pa1, mask, 64);
            pa2 += __shfl_xor(pa2, mask, 64);
            pa3 += __shfl_xor(pa3, mask, 64);
        }

        const int buf = t & 1;
        if (m == 0) {   // lanes 0,16,32,48: rows q*4..q*4+3, one ds_write_b128
            float4 v = make_float4(pa0, pa1, pa2, pa3);
            *(float4*)&sPart[buf][w][q * 4] = v;
        }
        __syncthreads();   // single barrier per step (ping-pong buffer)

        // every lane: final pred for its row m (cross-wave sum)
        float pred = b2v + sPart[buf][0][m] + sPart[buf][1][m]
                         + sPart[buf][2][m] + sPart[buf][3][m];
        if (w == 0 && lane < 16)
            out[row * T_STEPS + t] = pred;

        // shift feedback
        fb2 = fb1; fb1 = fb0; fb0 = pred;
    }
}

extern "C" void kernel_launch(void* const* d_in, const int* in_sizes, int n_in,
                              void* d_out, int out_size, void* d_ws, size_t ws_size,
                              hipStream_t stream) {
    const float* X  = (const float*)d_in[0];
    const float* y0 = (const float*)d_in[1];
    const float* W1 = (const float*)d_in[2];
    const float* b1 = (const float*)d_in[3];
    const float* W2 = (const float*)d_in[4];
    const float* b2 = (const float*)d_in[5];
    float* out = (float*)d_out;

    dim3 grid(B_TOT / 16);   // 1024 blocks (16 batch rows each)
    dim3 block(256);         // 4 waves
    narx_mfma<<<grid, block, 0, stream>>>(X, y0, W1, b1, W2, b2, out);
}